// Round 11
// baseline (119.210 us; speedup 1.0000x reference)
//
#include <hip/hip_runtime.h>
#include <hip/hip_bf16.h>
#include <stdint.h>

typedef __bf16 bf16_t;
typedef __bf16 bf16x8 __attribute__((ext_vector_type(8)));
typedef float f32x4 __attribute__((ext_vector_type(4)));

#define NB 2
#define NN 2048
#define ND 1024
#define NH 16
#define DHEAD 64
#define WIN 128

__device__ __forceinline__ void load_lds16(const void* g, void* l) {
  __builtin_amdgcn_global_load_lds(
      (const __attribute__((address_space(1))) uint32_t*)g,
      (__attribute__((address_space(3))) uint32_t*)l, 16, 0, 0);
}

// single merged cast launch: x (1048576 float4) + 4 weights (262144 float4 each)
__global__ __launch_bounds__(256)
void cast_all(const float* __restrict__ x,
              const float* __restrict__ Wq, const float* __restrict__ Wk,
              const float* __restrict__ Wv, const float* __restrict__ Wo,
              bf16_t* __restrict__ xb,
              bf16_t* __restrict__ Wqb, bf16_t* __restrict__ Wkb,
              bf16_t* __restrict__ Wvb, bf16_t* __restrict__ Wob) {
  int i = blockIdx.x * 256 + threadIdx.x;   // 0 .. 2097151
  const float* in;
  bf16_t* out;
  int off;
  if (i < 1048576) {
    in = x; out = xb; off = i;
  } else {
    int j = i - 1048576;
    int wsel = j >> 18;
    off = j & 262143;
    in  = (wsel == 0) ? Wq  : (wsel == 1) ? Wk  : (wsel == 2) ? Wv  : Wo;
    out = (wsel == 0) ? Wqb : (wsel == 1) ? Wkb : (wsel == 2) ? Wvb : Wob;
  }
  float4 v = reinterpret_cast<const float4*>(in)[off];
  union { bf16_t h[4]; uint2 u; } o;
  o.h[0] = (bf16_t)v.x; o.h[1] = (bf16_t)v.y;
  o.h[2] = (bf16_t)v.z; o.h[3] = (bf16_t)v.w;
  reinterpret_cast<uint2*>(out)[off] = o.u;
}

// ---------------------------------------------------------------------------
// QKV GEMM (frozen at best variant, R9): 128x128 tile, BK=32, 8 waves
// (2Mx4N, wave-tile 64x32), double-buffered 32KB LDS, conflict-free swizzle.
// ~600 TF — at the m97-structure's shape-limited ceiling for K=1024.
// ---------------------------------------------------------------------------
__global__ __launch_bounds__(512, 6)
void qkv_gemm(const bf16_t* __restrict__ xb,
              const bf16_t* __restrict__ Wqb, const bf16_t* __restrict__ Wkb,
              const bf16_t* __restrict__ Wvb,
              const float* __restrict__ bq, const float* __restrict__ bk,
              const float* __restrict__ bv,
              bf16_t* __restrict__ Qh, bf16_t* __restrict__ Kh,
              bf16_t* __restrict__ VTt) {
  __shared__ __align__(16) bf16_t As[2 * 4096];
  __shared__ __align__(16) bf16_t Bs[2 * 4096];

  const int z = blockIdx.z;
  const bf16_t* Bw  = (z == 0) ? Wqb : (z == 1) ? Wkb : Wvb;
  const float* bias = (z == 0) ? bq  : (z == 1) ? bk  : bv;
  const int m0 = blockIdx.y * 128, n0 = blockIdx.x * 128;

  const int tid = threadIdx.x, lane = tid & 63, w = tid >> 6;   // 8 waves
  const int wm = w >> 2, wn = w & 3;                            // 2 x 4 wave grid
  const int lrow = lane & 15, lkg = lane >> 4;
  const int sr = lane >> 2;                                     // 16 rows per gll
  const int sc = ((lane & 3) ^ ((lane >> 3) & 3)) * 8;          // inverse-swizzled src

  const bf16_t* abase = xb + (size_t)(m0 + w * 16 + sr) * 1024 + sc;
  const bf16_t* bbase = Bw + (size_t)(n0 + w * 16 + sr) * 1024 + sc;

  f32x4 acc[4][2] = {};

  auto stage = [&](int buf, int k0) {
    load_lds16(abase + k0, As + buf * 4096 + w * 512);
    load_lds16(bbase + k0, Bs + buf * 4096 + w * 512);
  };

  stage(0, 0);
  __syncthreads();

  for (int t = 0; t < 32; ++t) {
    if (t < 31) stage((t + 1) & 1, (t + 1) << 5);
    const bf16_t* Ab = As + (t & 1) * 4096;
    const bf16_t* Bb = Bs + (t & 1) * 4096;
    bf16x8 af[4], bf[2];
#pragma unroll
    for (int m = 0; m < 4; ++m) {
      const int row = wm * 64 + m * 16 + lrow;
      af[m] = *reinterpret_cast<const bf16x8*>(Ab + row * 32 + ((lkg ^ ((row >> 1) & 3)) << 3));
    }
#pragma unroll
    for (int n = 0; n < 2; ++n) {
      const int row = wn * 32 + n * 16 + lrow;
      bf[n] = *reinterpret_cast<const bf16x8*>(Bb + row * 32 + ((lkg ^ ((row >> 1) & 3)) << 3));
    }
#pragma unroll
    for (int m = 0; m < 4; ++m)
#pragma unroll
      for (int n = 0; n < 2; ++n)
        acc[m][n] = __builtin_amdgcn_mfma_f32_16x16x32_bf16(af[m], bf[n], acc[m][n], 0, 0, 0);
    __syncthreads();
  }

#pragma unroll
  for (int m = 0; m < 4; ++m)
#pragma unroll
    for (int n = 0; n < 2; ++n)
#pragma unroll
      for (int r = 0; r < 4; ++r) {
        int row = m0 + wm * 64 + m * 16 + lkg * 4 + r;   // token index (global)
        int col = n0 + wn * 32 + n * 16 + lrow;          // feature index
        float val = acc[m][n][r] + bias[col];
        int bb = row >> 11, tok = row & 2047;
        int hh = col >> 6,  dd = col & 63;
        if (z == 2) {
          VTt[((((size_t)(bb * NH + hh) * 32 + (tok >> 6)) * 64 + dd) << 6) + (tok & 63)] = (bf16_t)val;
        } else {
          bf16_t* outp = (z == 0) ? Qh : Kh;
          outp[(((size_t)(bb * NH + hh) * NN + tok) << 6) + dd] = (bf16_t)val;
        }
      }
}

// ---------------------------------------------------------------------------
// Output projection with in-block split-K (unchanged, proven R8).
// ---------------------------------------------------------------------------
__global__ __launch_bounds__(512, 2)
void out_gemm2(const bf16_t* __restrict__ AOb, const bf16_t* __restrict__ Wob,
               const float* __restrict__ bo, float* __restrict__ Cout) {
  __shared__ __align__(16) bf16_t lds[32768];   // [g*2+buf][A 4096 | B 4096]

  const int m0 = blockIdx.y * 128, n0 = blockIdx.x * 128;
  const int tid = threadIdx.x, lane = tid & 63, w = tid >> 6;
  const int g = w >> 2;
  const int pair = w & 3;
  const int wr = pair >> 1, wc = pair & 1;
  const int lrow = lane & 15, lkg = lane >> 4;
  const int rsw = (lrow >> 1) & 3;
  const int srow = lane >> 2;
  const int scol = ((lane & 3) ^ ((lane >> 3) & 3)) * 8;

  const bf16_t* abase = AOb + (size_t)(m0 + srow) * 1024 + g * 512 + scol;
  const bf16_t* bbase = Wob + (size_t)(n0 + srow) * 1024 + g * 512 + scol;

  f32x4 acc[4][4] = {};

  auto stage = [&](int buf, int k0) {
#pragma unroll
    for (int i = 0; i < 2; ++i) {
      const int rbase = (pair * 2 + i) * 16;
      bf16_t* seg = &lds[(g * 2 + buf) * 8192];
      load_lds16(abase + (size_t)rbase * 1024 + k0, seg + rbase * 32);
      load_lds16(bbase + (size_t)rbase * 1024 + k0, seg + 4096 + rbase * 32);
    }
  };

  stage(0, 0);
  __syncthreads();

  for (int t = 0; t < 16; ++t) {
    if (t < 15) stage((t + 1) & 1, (t + 1) << 5);
    const bf16_t* Ab = &lds[(g * 2 + (t & 1)) * 8192];
    const bf16_t* Bb = Ab + 4096;
    bf16x8 af[4], bf[4];
#pragma unroll
    for (int m = 0; m < 4; ++m)
      af[m] = *reinterpret_cast<const bf16x8*>(Ab + (wr * 64 + m * 16 + lrow) * 32 + ((lkg ^ rsw) << 3));
#pragma unroll
    for (int n = 0; n < 4; ++n)
      bf[n] = *reinterpret_cast<const bf16x8*>(Bb + (wc * 64 + n * 16 + lrow) * 32 + ((lkg ^ rsw) << 3));
#pragma unroll
    for (int m = 0; m < 4; ++m)
#pragma unroll
      for (int n = 0; n < 4; ++n)
        acc[m][n] = __builtin_amdgcn_mfma_f32_16x16x32_bf16(af[m], bf[n], acc[m][n], 0, 0, 0);
    __syncthreads();
  }

  float* fl = reinterpret_cast<float*>(lds);
  if (g == 1) {
#pragma unroll
    for (int m = 0; m < 4; ++m)
#pragma unroll
      for (int n = 0; n < 4; ++n)
#pragma unroll
        for (int r = 0; r < 4; ++r)
          fl[pair * 4096 + ((m * 4 + n) * 4 + r) * 64 + lane] = acc[m][n][r];
  }
  __syncthreads();
  if (g == 0) {
#pragma unroll
    for (int m = 0; m < 4; ++m)
#pragma unroll
      for (int n = 0; n < 4; ++n)
#pragma unroll
        for (int r = 0; r < 4; ++r) {
          int row = m0 + wr * 64 + m * 16 + lkg * 4 + r;
          int col = n0 + wc * 64 + n * 16 + lrow;
          float val = acc[m][n][r] + fl[pair * 4096 + ((m * 4 + n) * 4 + r) * 64 + lane] + bo[col];
          Cout[(size_t)row * 1024 + col] = val;
        }
  }
}

// ---------------------------------------------------------------------------
// BARRIER-FREE flash attention, swapped QK^T. K/V read directly from global
// (head-major K: dense 128B rows; tile-major V: dense 8KB tiles) — L2-resident
// (512KB per (b,h), ~5x reuse), so LDS staging was pure overhead (guide
// Common-mistake #7). Zero __syncthreads: P_lds is wave-private; waves drift
// freely and TLP hides L2 latency. LDS = 8KB -> high occupancy.
// ---------------------------------------------------------------------------
__global__ __launch_bounds__(256)
void attn_kernel(const bf16_t* __restrict__ Qh, const bf16_t* __restrict__ Kh,
                 const bf16_t* __restrict__ VTt, bf16_t* __restrict__ AO) {
  __shared__ uint32_t P_lds[4][16][32];

  const int work = ((blockIdx.x & 7) << 7) | (blockIdx.x >> 3);  // XCD-bijective
  const int qt = work & 31, h = (work >> 5) & 15, b = work >> 9;
  const int tid = threadIdx.x, lane = tid & 63, w = tid >> 6;
  const int lrow = lane & 15, lkg = lane >> 4;
  const int q0 = qt * 64;
  const int qb = q0 + w * 16;
  const int qrow = qb + lrow;
  const int rs7 = lrow & 7;

  const bf16_t* kbase = Kh  + (((size_t)(b * NH + h) * NN) << 6);
  const bf16_t* vbase = VTt + ((size_t)(b * NH + h) * 32) * 4096;

  const bf16_t* qptr = Qh + (((size_t)(b * NH + h) * NN + qrow) << 6) + lkg * 8;
  bf16x8 qf0 = *reinterpret_cast<const bf16x8*>(qptr);
  bf16x8 qf1 = *reinterpret_cast<const bf16x8*>(qptr + 32);

  float m_run = -1e30f, l_run = 0.f;
  f32x4 o[4] = {};

  const int kstart = (q0 - WIN > 0) ? (q0 - WIN) : 0;
  const int kend = (q0 + 64 + WIN < NN) ? (q0 + 64 + WIN) : NN;
  const float scale = 0.125f;

  for (int kc = kstart; kc < kend; kc += 64) {
    // ---- QK^T (swapped): K frags straight from global (dense 16-row blocks)
    f32x4 s[4];
#pragma unroll
    for (int t = 0; t < 4; ++t) {
      const bf16_t* kr = kbase + (((size_t)(kc + t * 16 + lrow)) << 6) + lkg * 8;
      bf16x8 kf0 = *reinterpret_cast<const bf16x8*>(kr);
      bf16x8 kf1 = *reinterpret_cast<const bf16x8*>(kr + 32);
      f32x4 zz = {};
      zz = __builtin_amdgcn_mfma_f32_16x16x32_bf16(kf0, qf0, zz, 0, 0, 0);
      zz = __builtin_amdgcn_mfma_f32_16x16x32_bf16(kf1, qf1, zz, 0, 0, 0);
      s[t] = zz;
    }

    // ---- V frags straight from global (dense 8KB tile), issued before softmax
    const bf16_t* vt = vbase + (size_t)(kc >> 6) * 4096;
    bf16x8 vf0[4], vf1[4];
#pragma unroll
    for (int f = 0; f < 4; ++f) {
      const bf16_t* vr = vt + (f * 16 + lrow) * 64 + lkg * 8;
      vf0[f] = *reinterpret_cast<const bf16x8*>(vr);
      vf1[f] = *reinterpret_cast<const bf16x8*>(vr + 32);
    }

    // ---- softmax (lane-local q-row)
    const bool needs_mask = (kc < qb - 113) || (kc > qb + 65);  // wave-uniform
    float p[4][4];
    float mloc = -1e30f, rsum = 0.f;
    if (needs_mask) {
      float v[4][4];
#pragma unroll
      for (int t = 0; t < 4; ++t)
#pragma unroll
        for (int r = 0; r < 4; ++r) {
          int k = kc + t * 16 + lkg * 4 + r;
          int d = qrow - k;
          bool ok = (unsigned)(d + WIN) <= 2u * WIN;
          v[t][r] = ok ? s[t][r] * scale : -1e30f;
          mloc = fmaxf(mloc, v[t][r]);
        }
      mloc = fmaxf(mloc, __shfl_xor(mloc, 16, 64));
      mloc = fmaxf(mloc, __shfl_xor(mloc, 32, 64));
      float mn = fmaxf(m_run, mloc);
      float corr = __expf(m_run - mn);
      m_run = mn;
#pragma unroll
      for (int t = 0; t < 4; ++t)
#pragma unroll
        for (int r = 0; r < 4; ++r) {
          int k = kc + t * 16 + lkg * 4 + r;
          int d = qrow - k;
          bool ok = (unsigned)(d + WIN) <= 2u * WIN;
          p[t][r] = ok ? __expf(v[t][r] - mn) : 0.f;
          rsum += p[t][r];
        }
      rsum += __shfl_xor(rsum, 16, 64);
      rsum += __shfl_xor(rsum, 32, 64);
      l_run = l_run * corr + rsum;
#pragma unroll
      for (int f = 0; f < 4; ++f) o[f] *= corr;
    } else {
      float v[4][4];
#pragma unroll
      for (int t = 0; t < 4; ++t)
#pragma unroll
        for (int r = 0; r < 4; ++r) {
          v[t][r] = s[t][r] * scale;
          mloc = fmaxf(mloc, v[t][r]);
        }
      mloc = fmaxf(mloc, __shfl_xor(mloc, 16, 64));
      mloc = fmaxf(mloc, __shfl_xor(mloc, 32, 64));
      float mn = fmaxf(m_run, mloc);
      float corr = __expf(m_run - mn);
      m_run = mn;
#pragma unroll
      for (int t = 0; t < 4; ++t)
#pragma unroll
        for (int r = 0; r < 4; ++r) {
          p[t][r] = __expf(v[t][r] - mn);
          rsum += p[t][r];
        }
      rsum += __shfl_xor(rsum, 16, 64);
      rsum += __shfl_xor(rsum, 32, 64);
      l_run = l_run * corr + rsum;
#pragma unroll
      for (int f = 0; f < 4; ++f) o[f] *= corr;
    }

    // ---- P -> wave-private swizzled LDS (no barrier; same-wave in-order)
    uint32_t* prow = &P_lds[w][lrow][0];
#pragma unroll
    for (int t = 0; t < 4; ++t)
#pragma unroll
      for (int c = 0; c < 2; ++c) {
        union { bf16_t hh[2]; uint32_t u; } pk;
        pk.hh[0] = (bf16_t)p[t][2 * c];
        pk.hh[1] = (bf16_t)p[t][2 * c + 1];
        int L = 8 * t + 2 * lkg + c;
        int pos = (((L >> 2) ^ rs7) << 2) | (L & 3);
        prow[pos] = pk.u;
      }
    asm volatile("" ::: "memory");
    const bf16_t* prd = reinterpret_cast<const bf16_t*>(&P_lds[w][lrow][0]);
    bf16x8 pa0 = *reinterpret_cast<const bf16x8*>(prd + ((lkg ^ rs7) << 3));
    bf16x8 pa1 = *reinterpret_cast<const bf16x8*>(prd + (((4 + lkg) ^ rs7) << 3));

    // ---- PV
#pragma unroll
    for (int f = 0; f < 4; ++f) {
      o[f] = __builtin_amdgcn_mfma_f32_16x16x32_bf16(vf0[f], pa0, o[f], 0, 0, 0);
      o[f] = __builtin_amdgcn_mfma_f32_16x16x32_bf16(vf1[f], pa1, o[f], 0, 0, 0);
    }
  }

  float inv = 1.0f / l_run;
#pragma unroll
  for (int f = 0; f < 4; ++f) {
    union { bf16_t hh[4]; uint2 u; } ov;
#pragma unroll
    for (int r = 0; r < 4; ++r) ov.hh[r] = (bf16_t)(o[f][r] * inv);
    bf16_t* op = AO + (size_t)((b * NN + qrow)) * ND + h * DHEAD + f * 16 + lkg * 4;
    *reinterpret_cast<uint2*>(op) = ov.u;
  }
}

extern "C" void kernel_launch(void* const* d_in, const int* in_sizes, int n_in,
                              void* d_out, int out_size, void* d_ws, size_t ws_size,
                              hipStream_t stream) {
  const float* x  = (const float*)d_in[0];
  const float* Wq = (const float*)d_in[1];
  const float* bq = (const float*)d_in[2];
  const float* Wk = (const float*)d_in[3];
  const float* bk = (const float*)d_in[4];
  const float* Wv = (const float*)d_in[5];
  const float* bv = (const float*)d_in[6];
  const float* Wo = (const float*)d_in[7];
  const float* bo = (const float*)d_in[8];
  float* out = (float*)d_out;

  bf16_t* ws  = (bf16_t*)d_ws;
  bf16_t* xb  = ws;
  bf16_t* Wqb = xb  + 4194304;
  bf16_t* Wkb = Wqb + 1048576;
  bf16_t* Wvb = Wkb + 1048576;
  bf16_t* Wob = Wvb + 1048576;
  bf16_t* Qh  = Wob + 1048576;
  bf16_t* Kh  = Qh  + 4194304;
  bf16_t* VTt = Kh  + 4194304;
  bf16_t* AOb = VTt + 4194304;

  cast_all<<<8192, 256, 0, stream>>>(x, Wq, Wk, Wv, Wo, xb, Wqb, Wkb, Wvb, Wob);

  qkv_gemm<<<dim3(8, 32, 3), 512, 0, stream>>>(xb, Wqb, Wkb, Wvb, bq, bk, bv, Qh, Kh, VTt);
  attn_kernel<<<1024, 256, 0, stream>>>(Qh, Kh, VTt, AOb);
  out_gemm2<<<dim3(8, 32), 512, 0, stream>>>(AOb, Wob, bo, out);
}

// Round 12
// 91.793 us; speedup vs baseline: 1.2987x; 1.2987x over previous
//
#include <hip/hip_runtime.h>
#include <hip/hip_bf16.h>
#include <stdint.h>

typedef __bf16 bf16_t;
typedef __bf16 bf16x8 __attribute__((ext_vector_type(8)));
typedef float f32x4 __attribute__((ext_vector_type(4)));

#define NB 2
#define NN 2048
#define ND 1024
#define NH 16
#define DHEAD 64
#define WIN 128

__device__ __forceinline__ void load_lds16(const void* g, void* l) {
  __builtin_amdgcn_global_load_lds(
      (const __attribute__((address_space(1))) uint32_t*)g,
      (__attribute__((address_space(3))) uint32_t*)l, 16, 0, 0);
}

// single merged cast launch: x (1048576 float4) + 4 weights (262144 float4 each)
__global__ __launch_bounds__(256)
void cast_all(const float* __restrict__ x,
              const float* __restrict__ Wq, const float* __restrict__ Wk,
              const float* __restrict__ Wv, const float* __restrict__ Wo,
              bf16_t* __restrict__ xb,
              bf16_t* __restrict__ Wqb, bf16_t* __restrict__ Wkb,
              bf16_t* __restrict__ Wvb, bf16_t* __restrict__ Wob) {
  int i = blockIdx.x * 256 + threadIdx.x;   // 0 .. 2097151
  const float* in;
  bf16_t* out;
  int off;
  if (i < 1048576) {
    in = x; out = xb; off = i;
  } else {
    int j = i - 1048576;
    int wsel = j >> 18;
    off = j & 262143;
    in  = (wsel == 0) ? Wq  : (wsel == 1) ? Wk  : (wsel == 2) ? Wv  : Wo;
    out = (wsel == 0) ? Wqb : (wsel == 1) ? Wkb : (wsel == 2) ? Wvb : Wob;
  }
  float4 v = reinterpret_cast<const float4*>(in)[off];
  union { bf16_t h[4]; uint2 u; } o;
  o.h[0] = (bf16_t)v.x; o.h[1] = (bf16_t)v.y;
  o.h[2] = (bf16_t)v.z; o.h[3] = (bf16_t)v.w;
  reinterpret_cast<uint2*>(out)[off] = o.u;
}

// ---------------------------------------------------------------------------
// QKV GEMM (frozen, R9 best): 128x128 tile, BK=32, 8 waves (2Mx4N, 64x32),
// double-buffered 32KB LDS, conflict-free swizzle. ~600 TF.
// ---------------------------------------------------------------------------
__global__ __launch_bounds__(512, 6)
void qkv_gemm(const bf16_t* __restrict__ xb,
              const bf16_t* __restrict__ Wqb, const bf16_t* __restrict__ Wkb,
              const bf16_t* __restrict__ Wvb,
              const float* __restrict__ bq, const float* __restrict__ bk,
              const float* __restrict__ bv,
              bf16_t* __restrict__ Qh, bf16_t* __restrict__ Kh,
              bf16_t* __restrict__ VTt) {
  __shared__ __align__(16) bf16_t As[2 * 4096];
  __shared__ __align__(16) bf16_t Bs[2 * 4096];

  const int z = blockIdx.z;
  const bf16_t* Bw  = (z == 0) ? Wqb : (z == 1) ? Wkb : Wvb;
  const float* bias = (z == 0) ? bq  : (z == 1) ? bk  : bv;
  const int m0 = blockIdx.y * 128, n0 = blockIdx.x * 128;

  const int tid = threadIdx.x, lane = tid & 63, w = tid >> 6;   // 8 waves
  const int wm = w >> 2, wn = w & 3;                            // 2 x 4 wave grid
  const int lrow = lane & 15, lkg = lane >> 4;
  const int sr = lane >> 2;                                     // 16 rows per gll
  const int sc = ((lane & 3) ^ ((lane >> 3) & 3)) * 8;          // inverse-swizzled src

  const bf16_t* abase = xb + (size_t)(m0 + w * 16 + sr) * 1024 + sc;
  const bf16_t* bbase = Bw + (size_t)(n0 + w * 16 + sr) * 1024 + sc;

  f32x4 acc[4][2] = {};

  auto stage = [&](int buf, int k0) {
    load_lds16(abase + k0, As + buf * 4096 + w * 512);
    load_lds16(bbase + k0, Bs + buf * 4096 + w * 512);
  };

  stage(0, 0);
  __syncthreads();

  for (int t = 0; t < 32; ++t) {
    if (t < 31) stage((t + 1) & 1, (t + 1) << 5);
    const bf16_t* Ab = As + (t & 1) * 4096;
    const bf16_t* Bb = Bs + (t & 1) * 4096;
    bf16x8 af[4], bf[2];
#pragma unroll
    for (int m = 0; m < 4; ++m) {
      const int row = wm * 64 + m * 16 + lrow;
      af[m] = *reinterpret_cast<const bf16x8*>(Ab + row * 32 + ((lkg ^ ((row >> 1) & 3)) << 3));
    }
#pragma unroll
    for (int n = 0; n < 2; ++n) {
      const int row = wn * 32 + n * 16 + lrow;
      bf[n] = *reinterpret_cast<const bf16x8*>(Bb + row * 32 + ((lkg ^ ((row >> 1) & 3)) << 3));
    }
#pragma unroll
    for (int m = 0; m < 4; ++m)
#pragma unroll
      for (int n = 0; n < 2; ++n)
        acc[m][n] = __builtin_amdgcn_mfma_f32_16x16x32_bf16(af[m], bf[n], acc[m][n], 0, 0, 0);
    __syncthreads();
  }

#pragma unroll
  for (int m = 0; m < 4; ++m)
#pragma unroll
    for (int n = 0; n < 2; ++n)
#pragma unroll
      for (int r = 0; r < 4; ++r) {
        int row = m0 + wm * 64 + m * 16 + lkg * 4 + r;   // token index (global)
        int col = n0 + wn * 32 + n * 16 + lrow;          // feature index
        float val = acc[m][n][r] + bias[col];
        int bb = row >> 11, tok = row & 2047;
        int hh = col >> 6,  dd = col & 63;
        if (z == 2) {
          VTt[((((size_t)(bb * NH + hh) * 32 + (tok >> 6)) * 64 + dd) << 6) + (tok & 63)] = (bf16_t)val;
        } else {
          bf16_t* outp = (z == 0) ? Qh : Kh;
          outp[(((size_t)(bb * NH + hh) * NN + tok) << 6) + dd] = (bf16_t)val;
        }
      }
}

// ---------------------------------------------------------------------------
// Output projection with in-block split-K (unchanged, proven R8).
// ---------------------------------------------------------------------------
__global__ __launch_bounds__(512, 2)
void out_gemm2(const bf16_t* __restrict__ AOb, const bf16_t* __restrict__ Wob,
               const float* __restrict__ bo, float* __restrict__ Cout) {
  __shared__ __align__(16) bf16_t lds[32768];   // [g*2+buf][A 4096 | B 4096]

  const int m0 = blockIdx.y * 128, n0 = blockIdx.x * 128;
  const int tid = threadIdx.x, lane = tid & 63, w = tid >> 6;
  const int g = w >> 2;
  const int pair = w & 3;
  const int wr = pair >> 1, wc = pair & 1;
  const int lrow = lane & 15, lkg = lane >> 4;
  const int rsw = (lrow >> 1) & 3;
  const int srow = lane >> 2;
  const int scol = ((lane & 3) ^ ((lane >> 3) & 3)) * 8;

  const bf16_t* abase = AOb + (size_t)(m0 + srow) * 1024 + g * 512 + scol;
  const bf16_t* bbase = Wob + (size_t)(n0 + srow) * 1024 + g * 512 + scol;

  f32x4 acc[4][4] = {};

  auto stage = [&](int buf, int k0) {
#pragma unroll
    for (int i = 0; i < 2; ++i) {
      const int rbase = (pair * 2 + i) * 16;
      bf16_t* seg = &lds[(g * 2 + buf) * 8192];
      load_lds16(abase + (size_t)rbase * 1024 + k0, seg + rbase * 32);
      load_lds16(bbase + (size_t)rbase * 1024 + k0, seg + 4096 + rbase * 32);
    }
  };

  stage(0, 0);
  __syncthreads();

  for (int t = 0; t < 16; ++t) {
    if (t < 15) stage((t + 1) & 1, (t + 1) << 5);
    const bf16_t* Ab = &lds[(g * 2 + (t & 1)) * 8192];
    const bf16_t* Bb = Ab + 4096;
    bf16x8 af[4], bf[4];
#pragma unroll
    for (int m = 0; m < 4; ++m)
      af[m] = *reinterpret_cast<const bf16x8*>(Ab + (wr * 64 + m * 16 + lrow) * 32 + ((lkg ^ rsw) << 3));
#pragma unroll
    for (int n = 0; n < 4; ++n)
      bf[n] = *reinterpret_cast<const bf16x8*>(Bb + (wc * 64 + n * 16 + lrow) * 32 + ((lkg ^ rsw) << 3));
#pragma unroll
    for (int m = 0; m < 4; ++m)
#pragma unroll
      for (int n = 0; n < 4; ++n)
        acc[m][n] = __builtin_amdgcn_mfma_f32_16x16x32_bf16(af[m], bf[n], acc[m][n], 0, 0, 0);
    __syncthreads();
  }

  float* fl = reinterpret_cast<float*>(lds);
  if (g == 1) {
#pragma unroll
    for (int m = 0; m < 4; ++m)
#pragma unroll
      for (int n = 0; n < 4; ++n)
#pragma unroll
        for (int r = 0; r < 4; ++r)
          fl[pair * 4096 + ((m * 4 + n) * 4 + r) * 64 + lane] = acc[m][n][r];
  }
  __syncthreads();
  if (g == 0) {
#pragma unroll
    for (int m = 0; m < 4; ++m)
#pragma unroll
      for (int n = 0; n < 4; ++n)
#pragma unroll
        for (int r = 0; r < 4; ++r) {
          int row = m0 + wr * 64 + m * 16 + lkg * 4 + r;
          int col = n0 + wc * 64 + n * 16 + lrow;
          float val = acc[m][n][r] + fl[pair * 4096 + ((m * 4 + n) * 4 + r) * 64 + lane] + bo[col];
          Cout[(size_t)row * 1024 + col] = val;
        }
  }
}

// ---------------------------------------------------------------------------
// Flash attention (R3 staged structure) with QBLK=128, 8 waves, and
// wave-uniform full-masked-chunk skip. Cooperative LDS staging de-duplicates
// cross-wave K/V reads (R11 lesson); staged bytes/chunk-barriers drop 1.6x
// vs QBLK=64. LDS = 32KB KV + 16KB P = 48KB.
// ---------------------------------------------------------------------------
__global__ __launch_bounds__(512)
void attn_kernel(const bf16_t* __restrict__ Qh, const bf16_t* __restrict__ Kh,
                 const bf16_t* __restrict__ VTt, bf16_t* __restrict__ AO) {
  __shared__ __align__(16) bf16_t KV_lds[2][2][4096];  // [buf][0=K,1=V][64 rows][64]
  __shared__ uint32_t P_lds[8][16][32];

  const int work = ((blockIdx.x & 7) << 6) | (blockIdx.x >> 3);  // XCD-bijective, 512 blocks
  const int qt = work & 15, h = (work >> 4) & 15, b = work >> 8;
  const int tid = threadIdx.x, lane = tid & 63, w = tid >> 6;    // 8 waves
  const int lrow = lane & 15, lkg = lane >> 4;
  const int q0 = qt * 128;
  const int qb = q0 + w * 16;
  const int qrow = qb + lrow;
  const int rs7 = lrow & 7;

  const int srow8 = lane >> 3;
  const int sswz  = 8 * ((lane & 7) ^ srow8);

  const bf16_t* kbase = Kh  + (((size_t)(b * NH + h) * NN) << 6);
  const bf16_t* vbase = VTt + ((size_t)(b * NH + h) * 32) * 4096;

  const bf16_t* qptr = Qh + (((size_t)(b * NH + h) * NN + qrow) << 6) + lkg * 8;
  bf16x8 qf0 = *reinterpret_cast<const bf16x8*>(qptr);
  bf16x8 qf1 = *reinterpret_cast<const bf16x8*>(qptr + 32);

  float m_run = -1e30f, l_run = 0.f;
  f32x4 o[4] = {};

  const int kstart = (q0 - WIN > 0) ? (q0 - WIN) : 0;
  const int kend = (q0 + 128 + WIN < NN) ? (q0 + 128 + WIN) : NN;  // multiple of 64
  const int nch = (kend - kstart) >> 6;
  const float scale = 0.125f;

  auto stage = [&](int bufi, int kc) {
    load_lds16(kbase + (((size_t)(kc + w * 8 + srow8)) << 6) + sswz,
               &KV_lds[bufi][0][w * 512]);
    load_lds16(vbase + (((size_t)((kc >> 6) * 64 + w * 8 + srow8)) << 6) + sswz,
               &KV_lds[bufi][1][w * 512]);
  };

  stage(0, kstart);
  __syncthreads();

  for (int ic = 0; ic < nch; ++ic) {
    const int kc = kstart + ic * 64;
    const int bi = ic & 1;
    if (ic + 1 < nch) stage(bi ^ 1, kc + 64);

    // wave-uniform: chunk fully outside this wave's window [qb-128, qb+15+128]?
    const bool skip = (kc > qb + 143) || (kc + 63 < qb - 128);
    if (!skip) {
      const bf16_t* Kt = &KV_lds[bi][0][0];
      const bf16_t* Vt = &KV_lds[bi][1][0];

      f32x4 s[4];
#pragma unroll
      for (int t = 0; t < 4; ++t) {
        const bf16_t* kr = Kt + (t * 16 + lrow) * 64;
        bf16x8 kf0 = *reinterpret_cast<const bf16x8*>(kr + ((lkg ^ rs7) << 3));
        bf16x8 kf1 = *reinterpret_cast<const bf16x8*>(kr + (((4 + lkg) ^ rs7) << 3));
        f32x4 zz = {};
        zz = __builtin_amdgcn_mfma_f32_16x16x32_bf16(kf0, qf0, zz, 0, 0, 0);
        zz = __builtin_amdgcn_mfma_f32_16x16x32_bf16(kf1, qf1, zz, 0, 0, 0);
        s[t] = zz;
      }

      bf16x8 vf0[4], vf1[4];
#pragma unroll
      for (int f = 0; f < 4; ++f) {
        const bf16_t* vr = Vt + (f * 16 + lrow) * 64;
        vf0[f] = *reinterpret_cast<const bf16x8*>(vr + ((lkg ^ rs7) << 3));
        vf1[f] = *reinterpret_cast<const bf16x8*>(vr + (((4 + lkg) ^ rs7) << 3));
      }

      const bool needs_mask = (kc < qb - 113) || (kc > qb + 65);
      float p[4][4];
      float mloc = -1e30f, rsum = 0.f;
      if (needs_mask) {
        float v[4][4];
#pragma unroll
        for (int t = 0; t < 4; ++t)
#pragma unroll
          for (int r = 0; r < 4; ++r) {
            int k = kc + t * 16 + lkg * 4 + r;
            int d = qrow - k;
            bool ok = (unsigned)(d + WIN) <= 2u * WIN;
            v[t][r] = ok ? s[t][r] * scale : -1e30f;
            mloc = fmaxf(mloc, v[t][r]);
          }
        mloc = fmaxf(mloc, __shfl_xor(mloc, 16, 64));
        mloc = fmaxf(mloc, __shfl_xor(mloc, 32, 64));
        float mn = fmaxf(m_run, mloc);
        float corr = __expf(m_run - mn);
        m_run = mn;
#pragma unroll
        for (int t = 0; t < 4; ++t)
#pragma unroll
          for (int r = 0; r < 4; ++r) {
            int k = kc + t * 16 + lkg * 4 + r;
            int d = qrow - k;
            bool ok = (unsigned)(d + WIN) <= 2u * WIN;
            p[t][r] = ok ? __expf(v[t][r] - mn) : 0.f;
            rsum += p[t][r];
          }
        rsum += __shfl_xor(rsum, 16, 64);
        rsum += __shfl_xor(rsum, 32, 64);
        l_run = l_run * corr + rsum;
#pragma unroll
        for (int f = 0; f < 4; ++f) o[f] *= corr;
      } else {
        float v[4][4];
#pragma unroll
        for (int t = 0; t < 4; ++t)
#pragma unroll
          for (int r = 0; r < 4; ++r) {
            v[t][r] = s[t][r] * scale;
            mloc = fmaxf(mloc, v[t][r]);
          }
        mloc = fmaxf(mloc, __shfl_xor(mloc, 16, 64));
        mloc = fmaxf(mloc, __shfl_xor(mloc, 32, 64));
        float mn = fmaxf(m_run, mloc);
        float corr = __expf(m_run - mn);
        m_run = mn;
#pragma unroll
        for (int t = 0; t < 4; ++t)
#pragma unroll
          for (int r = 0; r < 4; ++r) {
            p[t][r] = __expf(v[t][r] - mn);
            rsum += p[t][r];
          }
        rsum += __shfl_xor(rsum, 16, 64);
        rsum += __shfl_xor(rsum, 32, 64);
        l_run = l_run * corr + rsum;
#pragma unroll
        for (int f = 0; f < 4; ++f) o[f] *= corr;
      }

      uint32_t* prow = &P_lds[w][lrow][0];
#pragma unroll
      for (int t = 0; t < 4; ++t)
#pragma unroll
        for (int c = 0; c < 2; ++c) {
          union { bf16_t hh[2]; uint32_t u; } pk;
          pk.hh[0] = (bf16_t)p[t][2 * c];
          pk.hh[1] = (bf16_t)p[t][2 * c + 1];
          int L = 8 * t + 2 * lkg + c;
          int pos = (((L >> 2) ^ rs7) << 2) | (L & 3);
          prow[pos] = pk.u;
        }
      asm volatile("" ::: "memory");
      const bf16_t* prd = reinterpret_cast<const bf16_t*>(&P_lds[w][lrow][0]);
      bf16x8 pa0 = *reinterpret_cast<const bf16x8*>(prd + ((lkg ^ rs7) << 3));
      bf16x8 pa1 = *reinterpret_cast<const bf16x8*>(prd + (((4 + lkg) ^ rs7) << 3));

#pragma unroll
      for (int f = 0; f < 4; ++f) {
        o[f] = __builtin_amdgcn_mfma_f32_16x16x32_bf16(vf0[f], pa0, o[f], 0, 0, 0);
        o[f] = __builtin_amdgcn_mfma_f32_16x16x32_bf16(vf1[f], pa1, o[f], 0, 0, 0);
      }
    }
    __syncthreads();   // drains stage vmcnt + protects buffer reuse
  }

  float inv = 1.0f / l_run;
#pragma unroll
  for (int f = 0; f < 4; ++f) {
    union { bf16_t hh[4]; uint2 u; } ov;
#pragma unroll
    for (int r = 0; r < 4; ++r) ov.hh[r] = (bf16_t)(o[f][r] * inv);
    bf16_t* op = AO + (size_t)(b * NN + qrow) * ND + h * DHEAD + f * 16 + lkg * 4;
    *reinterpret_cast<uint2*>(op) = ov.u;
  }
}

extern "C" void kernel_launch(void* const* d_in, const int* in_sizes, int n_in,
                              void* d_out, int out_size, void* d_ws, size_t ws_size,
                              hipStream_t stream) {
  const float* x  = (const float*)d_in[0];
  const float* Wq = (const float*)d_in[1];
  const float* bq = (const float*)d_in[2];
  const float* Wk = (const float*)d_in[3];
  const float* bk = (const float*)d_in[4];
  const float* Wv = (const float*)d_in[5];
  const float* bv = (const float*)d_in[6];
  const float* Wo = (const float*)d_in[7];
  const float* bo = (const float*)d_in[8];
  float* out = (float*)d_out;

  bf16_t* ws  = (bf16_t*)d_ws;
  bf16_t* xb  = ws;
  bf16_t* Wqb = xb  + 4194304;
  bf16_t* Wkb = Wqb + 1048576;
  bf16_t* Wvb = Wkb + 1048576;
  bf16_t* Wob = Wvb + 1048576;
  bf16_t* Qh  = Wob + 1048576;
  bf16_t* Kh  = Qh  + 4194304;
  bf16_t* VTt = Kh  + 4194304;
  bf16_t* AOb = VTt + 4194304;

  cast_all<<<8192, 256, 0, stream>>>(x, Wq, Wk, Wv, Wo, xb, Wqb, Wkb, Wvb, Wob);

  qkv_gemm<<<dim3(8, 32, 3), 512, 0, stream>>>(xb, Wqb, Wkb, Wvb, bq, bk, bv, Qh, Kh, VTt);
  attn_kernel<<<512, 512, 0, stream>>>(Qh, Kh, VTt, AOb);
  out_gemm2<<<dim3(8, 32), 512, 0, stream>>>(AOb, Wob, bo, out);
}

// Round 13
// 91.294 us; speedup vs baseline: 1.3058x; 1.0055x over previous
//
#include <hip/hip_runtime.h>
#include <hip/hip_bf16.h>
#include <stdint.h>

typedef __bf16 bf16_t;
typedef __bf16 bf16x8 __attribute__((ext_vector_type(8)));
typedef float f32x4 __attribute__((ext_vector_type(4)));

#define NB 2
#define NN 2048
#define ND 1024
#define NH 16
#define DHEAD 64
#define WIN 128

__device__ __forceinline__ void load_lds16(const void* g, void* l) {
  __builtin_amdgcn_global_load_lds(
      (const __attribute__((address_space(1))) uint32_t*)g,
      (__attribute__((address_space(3))) uint32_t*)l, 16, 0, 0);
}

// single merged cast launch: x (1048576 float4) + 4 weights (262144 float4 each)
__global__ __launch_bounds__(256)
void cast_all(const float* __restrict__ x,
              const float* __restrict__ Wq, const float* __restrict__ Wk,
              const float* __restrict__ Wv, const float* __restrict__ Wo,
              bf16_t* __restrict__ xb,
              bf16_t* __restrict__ Wqb, bf16_t* __restrict__ Wkb,
              bf16_t* __restrict__ Wvb, bf16_t* __restrict__ Wob) {
  int i = blockIdx.x * 256 + threadIdx.x;   // 0 .. 2097151
  const float* in;
  bf16_t* out;
  int off;
  if (i < 1048576) {
    in = x; out = xb; off = i;
  } else {
    int j = i - 1048576;
    int wsel = j >> 18;
    off = j & 262143;
    in  = (wsel == 0) ? Wq  : (wsel == 1) ? Wk  : (wsel == 2) ? Wv  : Wo;
    out = (wsel == 0) ? Wqb : (wsel == 1) ? Wkb : (wsel == 2) ? Wvb : Wob;
  }
  float4 v = reinterpret_cast<const float4*>(in)[off];
  union { bf16_t h[4]; uint2 u; } o;
  o.h[0] = (bf16_t)v.x; o.h[1] = (bf16_t)v.y;
  o.h[2] = (bf16_t)v.z; o.h[3] = (bf16_t)v.w;
  reinterpret_cast<uint2*>(out)[off] = o.u;
}

// ---------------------------------------------------------------------------
// QKV GEMM (frozen, R9 best): 128x128 tile, BK=32, 8 waves (2Mx4N, 64x32),
// double-buffered 32KB LDS, conflict-free swizzle. ~600 TF.
// ---------------------------------------------------------------------------
__global__ __launch_bounds__(512, 6)
void qkv_gemm(const bf16_t* __restrict__ xb,
              const bf16_t* __restrict__ Wqb, const bf16_t* __restrict__ Wkb,
              const bf16_t* __restrict__ Wvb,
              const float* __restrict__ bq, const float* __restrict__ bk,
              const float* __restrict__ bv,
              bf16_t* __restrict__ Qh, bf16_t* __restrict__ Kh,
              bf16_t* __restrict__ VTt) {
  __shared__ __align__(16) bf16_t As[2 * 4096];
  __shared__ __align__(16) bf16_t Bs[2 * 4096];

  const int z = blockIdx.z;
  const bf16_t* Bw  = (z == 0) ? Wqb : (z == 1) ? Wkb : Wvb;
  const float* bias = (z == 0) ? bq  : (z == 1) ? bk  : bv;
  const int m0 = blockIdx.y * 128, n0 = blockIdx.x * 128;

  const int tid = threadIdx.x, lane = tid & 63, w = tid >> 6;   // 8 waves
  const int wm = w >> 2, wn = w & 3;                            // 2 x 4 wave grid
  const int lrow = lane & 15, lkg = lane >> 4;
  const int sr = lane >> 2;                                     // 16 rows per gll
  const int sc = ((lane & 3) ^ ((lane >> 3) & 3)) * 8;          // inverse-swizzled src

  const bf16_t* abase = xb + (size_t)(m0 + w * 16 + sr) * 1024 + sc;
  const bf16_t* bbase = Bw + (size_t)(n0 + w * 16 + sr) * 1024 + sc;

  f32x4 acc[4][2] = {};

  auto stage = [&](int buf, int k0) {
    load_lds16(abase + k0, As + buf * 4096 + w * 512);
    load_lds16(bbase + k0, Bs + buf * 4096 + w * 512);
  };

  stage(0, 0);
  __syncthreads();

  for (int t = 0; t < 32; ++t) {
    if (t < 31) stage((t + 1) & 1, (t + 1) << 5);
    const bf16_t* Ab = As + (t & 1) * 4096;
    const bf16_t* Bb = Bs + (t & 1) * 4096;
    bf16x8 af[4], bf[2];
#pragma unroll
    for (int m = 0; m < 4; ++m) {
      const int row = wm * 64 + m * 16 + lrow;
      af[m] = *reinterpret_cast<const bf16x8*>(Ab + row * 32 + ((lkg ^ ((row >> 1) & 3)) << 3));
    }
#pragma unroll
    for (int n = 0; n < 2; ++n) {
      const int row = wn * 32 + n * 16 + lrow;
      bf[n] = *reinterpret_cast<const bf16x8*>(Bb + row * 32 + ((lkg ^ ((row >> 1) & 3)) << 3));
    }
#pragma unroll
    for (int m = 0; m < 4; ++m)
#pragma unroll
      for (int n = 0; n < 2; ++n)
        acc[m][n] = __builtin_amdgcn_mfma_f32_16x16x32_bf16(af[m], bf[n], acc[m][n], 0, 0, 0);
    __syncthreads();
  }

#pragma unroll
  for (int m = 0; m < 4; ++m)
#pragma unroll
    for (int n = 0; n < 2; ++n)
#pragma unroll
      for (int r = 0; r < 4; ++r) {
        int row = m0 + wm * 64 + m * 16 + lkg * 4 + r;   // token index (global)
        int col = n0 + wn * 32 + n * 16 + lrow;          // feature index
        float val = acc[m][n][r] + bias[col];
        int bb = row >> 11, tok = row & 2047;
        int hh = col >> 6,  dd = col & 63;
        if (z == 2) {
          VTt[((((size_t)(bb * NH + hh) * 32 + (tok >> 6)) * 64 + dd) << 6) + (tok & 63)] = (bf16_t)val;
        } else {
          bf16_t* outp = (z == 0) ? Qh : Kh;
          outp[(((size_t)(bb * NH + hh) * NN + tok) << 6) + dd] = (bf16_t)val;
        }
      }
}

// ---------------------------------------------------------------------------
// Output projection: 128x64 tiles -> grid 512 (2 blocks/CU) + in-block
// split-K (8 waves = 2 K-groups x 4 waves of 64x32 wave-tiles, qkv's proven
// shape). Dbuf + swizzle. LDS 48KB: per (g,buf) segment A[128x32]|B[64x32].
// ---------------------------------------------------------------------------
__global__ __launch_bounds__(512, 2)
void out_gemm3(const bf16_t* __restrict__ AOb, const bf16_t* __restrict__ Wob,
               const float* __restrict__ bo, float* __restrict__ Cout) {
  __shared__ __align__(16) bf16_t lds[24576];   // 4 segs x 6144 elem (A 4096 | B 2048)

  const int m0 = blockIdx.y * 128, n0 = blockIdx.x * 64;
  const int tid = threadIdx.x, lane = tid & 63, w = tid >> 6;
  const int g = w >> 2;                          // K-group: K[g*512, g*512+512)
  const int pr = w & 3;                          // wave id within group
  const int wr = pr >> 1, wc = pr & 1;           // 2M x 2N
  const int lrow = lane & 15, lkg = lane >> 4;
  const int sr = lane >> 2;
  const int sc = ((lane & 3) ^ ((lane >> 3) & 3)) * 8;

  const bf16_t* abase = AOb + (size_t)(m0 + sr) * 1024 + g * 512 + sc;
  const bf16_t* bbase = Wob + (size_t)(n0 + pr * 16 + sr) * 1024 + g * 512 + sc;

  f32x4 acc[4][2] = {};

  auto stage = [&](int buf, int k0) {
    bf16_t* seg = &lds[(g * 2 + buf) * 6144];
#pragma unroll
    for (int i = 0; i < 2; ++i) {
      const int unit = pr * 2 + i;               // 0..7 -> A rows unit*16..+15
      load_lds16(abase + (size_t)unit * 16 * 1024 + k0, seg + unit * 512);
    }
    load_lds16(bbase + k0, seg + 4096 + pr * 512);   // B rows pr*16..+15
  };

  stage(0, 0);
  __syncthreads();

  for (int t = 0; t < 16; ++t) {
    if (t < 15) stage((t + 1) & 1, (t + 1) << 5);
    const bf16_t* seg = &lds[(g * 2 + (t & 1)) * 6144];
    const bf16_t* Bb = seg + 4096;
    bf16x8 af[4], bf[2];
#pragma unroll
    for (int m = 0; m < 4; ++m) {
      const int row = wr * 64 + m * 16 + lrow;
      af[m] = *reinterpret_cast<const bf16x8*>(seg + row * 32 + ((lkg ^ ((row >> 1) & 3)) << 3));
    }
#pragma unroll
    for (int n = 0; n < 2; ++n) {
      const int row = wc * 32 + n * 16 + lrow;
      bf[n] = *reinterpret_cast<const bf16x8*>(Bb + row * 32 + ((lkg ^ ((row >> 1) & 3)) << 3));
    }
#pragma unroll
    for (int m = 0; m < 4; ++m)
#pragma unroll
      for (int n = 0; n < 2; ++n)
        acc[m][n] = __builtin_amdgcn_mfma_f32_16x16x32_bf16(af[m], bf[n], acc[m][n], 0, 0, 0);
    __syncthreads();
  }

  // split-K reduce: group 1 parks partials (32KB fits in 48KB LDS), group 0 adds
  float* fl = reinterpret_cast<float*>(lds);
  if (g == 1) {
#pragma unroll
    for (int m = 0; m < 4; ++m)
#pragma unroll
      for (int n = 0; n < 2; ++n)
#pragma unroll
        for (int r = 0; r < 4; ++r)
          fl[pr * 2048 + ((m * 2 + n) * 4 + r) * 64 + lane] = acc[m][n][r];
  }
  __syncthreads();
  if (g == 0) {
#pragma unroll
    for (int m = 0; m < 4; ++m)
#pragma unroll
      for (int n = 0; n < 2; ++n)
#pragma unroll
        for (int r = 0; r < 4; ++r) {
          int row = m0 + wr * 64 + m * 16 + lkg * 4 + r;
          int col = n0 + wc * 32 + n * 16 + lrow;
          float val = acc[m][n][r] + fl[pr * 2048 + ((m * 2 + n) * 4 + r) * 64 + lane] + bo[col];
          Cout[(size_t)row * 1024 + col] = val;
        }
  }
}

// ---------------------------------------------------------------------------
// Block-cooperative flash attention, swapped QK^T (proven R3/R8 version).
// ---------------------------------------------------------------------------
__global__ __launch_bounds__(256)
void attn_kernel(const bf16_t* __restrict__ Qh, const bf16_t* __restrict__ Kh,
                 const bf16_t* __restrict__ VTt, bf16_t* __restrict__ AO) {
  __shared__ __align__(16) bf16_t KV_lds[2][2][4096];
  __shared__ uint32_t P_lds[4][16][32];

  const int work = ((blockIdx.x & 7) << 7) | (blockIdx.x >> 3);
  const int qt = work & 31, h = (work >> 5) & 15, b = work >> 9;
  const int tid = threadIdx.x, lane = tid & 63, w = tid >> 6;
  const int lrow = lane & 15, lkg = lane >> 4;
  const int q0 = qt * 64;
  const int qb = q0 + w * 16;
  const int qrow = qb + lrow;
  const int rs7 = lrow & 7;

  const int srow8 = lane >> 3;
  const int sswz  = 8 * ((lane & 7) ^ srow8);

  const bf16_t* kbase = Kh  + (((size_t)(b * NH + h) * NN) << 6);
  const bf16_t* vbase = VTt + ((size_t)(b * NH + h) * 32) * 4096;

  const bf16_t* qptr = Qh + (((size_t)(b * NH + h) * NN + qrow) << 6) + lkg * 8;
  bf16x8 qf0 = *reinterpret_cast<const bf16x8*>(qptr);
  bf16x8 qf1 = *reinterpret_cast<const bf16x8*>(qptr + 32);

  float m_run = -1e30f, l_run = 0.f;
  f32x4 o[4] = {};

  const int kstart = (q0 - WIN > 0) ? (q0 - WIN) : 0;
  const int kend = (q0 + 64 + WIN < NN) ? (q0 + 64 + WIN) : NN;
  const int nch = (kend - kstart) >> 6;
  const float scale = 0.125f;

  auto stage = [&](int bufi, int kc) {
#pragma unroll
    for (int j = 0; j < 2; ++j) {
      const int i = w * 2 + j;
      load_lds16(kbase + (((size_t)(kc + i * 8 + srow8)) << 6) + sswz,
                 &KV_lds[bufi][0][i * 512]);
      load_lds16(vbase + (((size_t)((kc >> 6) * 64 + i * 8 + srow8)) << 6) + sswz,
                 &KV_lds[bufi][1][i * 512]);
    }
  };

  stage(0, kstart);
  __syncthreads();

  for (int ic = 0; ic < nch; ++ic) {
    const int kc = kstart + ic * 64;
    const int bi = ic & 1;
    if (ic + 1 < nch) stage(bi ^ 1, kc + 64);

    const bf16_t* Kt = &KV_lds[bi][0][0];
    const bf16_t* Vt = &KV_lds[bi][1][0];

    f32x4 s[4];
#pragma unroll
    for (int t = 0; t < 4; ++t) {
      const bf16_t* kr = Kt + (t * 16 + lrow) * 64;
      bf16x8 kf0 = *reinterpret_cast<const bf16x8*>(kr + ((lkg ^ rs7) << 3));
      bf16x8 kf1 = *reinterpret_cast<const bf16x8*>(kr + (((4 + lkg) ^ rs7) << 3));
      f32x4 zz = {};
      zz = __builtin_amdgcn_mfma_f32_16x16x32_bf16(kf0, qf0, zz, 0, 0, 0);
      zz = __builtin_amdgcn_mfma_f32_16x16x32_bf16(kf1, qf1, zz, 0, 0, 0);
      s[t] = zz;
    }

    bf16x8 vf0[4], vf1[4];
#pragma unroll
    for (int f = 0; f < 4; ++f) {
      const bf16_t* vr = Vt + (f * 16 + lrow) * 64;
      vf0[f] = *reinterpret_cast<const bf16x8*>(vr + ((lkg ^ rs7) << 3));
      vf1[f] = *reinterpret_cast<const bf16x8*>(vr + (((4 + lkg) ^ rs7) << 3));
    }

    const bool needs_mask = (kc < qb - 113) || (kc > qb + 65);
    float p[4][4];
    float mloc = -1e30f, rsum = 0.f;
    if (needs_mask) {
      float v[4][4];
#pragma unroll
      for (int t = 0; t < 4; ++t)
#pragma unroll
        for (int r = 0; r < 4; ++r) {
          int k = kc + t * 16 + lkg * 4 + r;
          int d = qrow - k;
          bool ok = (unsigned)(d + WIN) <= 2u * WIN;
          v[t][r] = ok ? s[t][r] * scale : -1e30f;
          mloc = fmaxf(mloc, v[t][r]);
        }
      mloc = fmaxf(mloc, __shfl_xor(mloc, 16, 64));
      mloc = fmaxf(mloc, __shfl_xor(mloc, 32, 64));
      float mn = fmaxf(m_run, mloc);
      float corr = __expf(m_run - mn);
      m_run = mn;
#pragma unroll
      for (int t = 0; t < 4; ++t)
#pragma unroll
        for (int r = 0; r < 4; ++r) {
          int k = kc + t * 16 + lkg * 4 + r;
          int d = qrow - k;
          bool ok = (unsigned)(d + WIN) <= 2u * WIN;
          p[t][r] = ok ? __expf(v[t][r] - mn) : 0.f;
          rsum += p[t][r];
        }
      rsum += __shfl_xor(rsum, 16, 64);
      rsum += __shfl_xor(rsum, 32, 64);
      l_run = l_run * corr + rsum;
#pragma unroll
      for (int f = 0; f < 4; ++f) o[f] *= corr;
    } else {
      float v[4][4];
#pragma unroll
      for (int t = 0; t < 4; ++t)
#pragma unroll
        for (int r = 0; r < 4; ++r) {
          v[t][r] = s[t][r] * scale;
          mloc = fmaxf(mloc, v[t][r]);
        }
      mloc = fmaxf(mloc, __shfl_xor(mloc, 16, 64));
      mloc = fmaxf(mloc, __shfl_xor(mloc, 32, 64));
      float mn = fmaxf(m_run, mloc);
      float corr = __expf(m_run - mn);
      m_run = mn;
#pragma unroll
      for (int t = 0; t < 4; ++t)
#pragma unroll
        for (int r = 0; r < 4; ++r) {
          p[t][r] = __expf(v[t][r] - mn);
          rsum += p[t][r];
        }
      rsum += __shfl_xor(rsum, 16, 64);
      rsum += __shfl_xor(rsum, 32, 64);
      l_run = l_run * corr + rsum;
#pragma unroll
      for (int f = 0; f < 4; ++f) o[f] *= corr;
    }

    uint32_t* prow = &P_lds[w][lrow][0];
#pragma unroll
    for (int t = 0; t < 4; ++t)
#pragma unroll
      for (int c = 0; c < 2; ++c) {
        union { bf16_t hh[2]; uint32_t u; } pk;
        pk.hh[0] = (bf16_t)p[t][2 * c];
        pk.hh[1] = (bf16_t)p[t][2 * c + 1];
        int L = 8 * t + 2 * lkg + c;
        int pos = (((L >> 2) ^ rs7) << 2) | (L & 3);
        prow[pos] = pk.u;
      }
    asm volatile("" ::: "memory");
    const bf16_t* prd = reinterpret_cast<const bf16_t*>(&P_lds[w][lrow][0]);
    bf16x8 pa0 = *reinterpret_cast<const bf16x8*>(prd + ((lkg ^ rs7) << 3));
    bf16x8 pa1 = *reinterpret_cast<const bf16x8*>(prd + (((4 + lkg) ^ rs7) << 3));

#pragma unroll
    for (int f = 0; f < 4; ++f) {
      o[f] = __builtin_amdgcn_mfma_f32_16x16x32_bf16(vf0[f], pa0, o[f], 0, 0, 0);
      o[f] = __builtin_amdgcn_mfma_f32_16x16x32_bf16(vf1[f], pa1, o[f], 0, 0, 0);
    }
    __syncthreads();
  }

  float inv = 1.0f / l_run;
#pragma unroll
  for (int f = 0; f < 4; ++f) {
    union { bf16_t hh[4]; uint2 u; } ov;
#pragma unroll
    for (int r = 0; r < 4; ++r) ov.hh[r] = (bf16_t)(o[f][r] * inv);
    bf16_t* op = AO + (size_t)(b * NN + qrow) * ND + h * DHEAD + f * 16 + lkg * 4;
    *reinterpret_cast<uint2*>(op) = ov.u;
  }
}

extern "C" void kernel_launch(void* const* d_in, const int* in_sizes, int n_in,
                              void* d_out, int out_size, void* d_ws, size_t ws_size,
                              hipStream_t stream) {
  const float* x  = (const float*)d_in[0];
  const float* Wq = (const float*)d_in[1];
  const float* bq = (const float*)d_in[2];
  const float* Wk = (const float*)d_in[3];
  const float* bk = (const float*)d_in[4];
  const float* Wv = (const float*)d_in[5];
  const float* bv = (const float*)d_in[6];
  const float* Wo = (const float*)d_in[7];
  const float* bo = (const float*)d_in[8];
  float* out = (float*)d_out;

  bf16_t* ws  = (bf16_t*)d_ws;
  bf16_t* xb  = ws;
  bf16_t* Wqb = xb  + 4194304;
  bf16_t* Wkb = Wqb + 1048576;
  bf16_t* Wvb = Wkb + 1048576;
  bf16_t* Wob = Wvb + 1048576;
  bf16_t* Qh  = Wob + 1048576;
  bf16_t* Kh  = Qh  + 4194304;
  bf16_t* VTt = Kh  + 4194304;
  bf16_t* AOb = VTt + 4194304;

  cast_all<<<8192, 256, 0, stream>>>(x, Wq, Wk, Wv, Wo, xb, Wqb, Wkb, Wvb, Wob);

  qkv_gemm<<<dim3(8, 32, 3), 512, 0, stream>>>(xb, Wqb, Wkb, Wvb, bq, bk, bv, Qh, Kh, VTt);
  attn_kernel<<<1024, 256, 0, stream>>>(Qh, Kh, VTt, AOb);
  out_gemm3<<<dim3(16, 32), 512, 0, stream>>>(AOb, Wob, bo, out);
}